// Round 5
// baseline (1212.515 us; speedup 1.0000x reference)
//
#include <hip/hip_runtime.h>

// Kalman filter, B=8192, M=4, N=8, T=512.
// K_t (gain) is data-independent -> kf_cov2 computes all 512 gains once
// (single wave, 2 LDS round-trips/iter, shuffles for small stages, full
// Joseph update: simple form P-KHP diverges to NaN in fp32 by t~500 (R3);
// gain freeze at t=96 gave 0.56 absmax (R2) -> compute all 512 exactly).
// Mean recursion parallelized 8x in time (affine scan):
//   mu_t = A_t mu_{t-1} + K_t x_t,  A_t = F - K_t G,  G = H F (uniform)
//   chunk c: mu_end = Phi_c mu_start + v_c ; v_c,Phi_c data-(in)dependent.

#define B_BATCH 8192
#define M_MEAS 4
#define N_ST 8
#define T_STEPS 512
#define NCHUNK 8
#define LCHUNK 64   // T_STEPS / NCHUNK

// ws layout (floats): K [0,16384) | PHI [16384,16896) | V [16896, +8*8192*8)
#define WS_K 0
#define WS_PHI 16384
#define WS_V 16896
#define WS_NEED_BYTES ((16384 + 512 + 8 * 8192 * 8) * 4)

// ---------------- Kernel 1: Riccati / gain recursion (1 block, 1 wave) -----
// lane = 8*i + j; lane (i,j) owns element (i,j) of 8x8 matrices.
__global__ __launch_bounds__(64) void kf_cov2(
    const float* __restrict__ Fp, const float* __restrict__ Hp,
    const float* __restrict__ Qp, const float* __restrict__ Rp,
    const float* __restrict__ stdp, float* __restrict__ Kws)
{
    const int lane = threadIdx.x;
    const int i = lane >> 3, j = lane & 7;
    __shared__ float4 Pm4[16], Pp4[16];
    float* Pm = (float*)Pm4;
    float* Pp = (float*)Pp4;

    // per-lane F rows i and j; full H, R (uniform per lane)
    float Fi[8], Fj[8];
#pragma unroll
    for (int k = 0; k < 8; ++k) { Fi[k] = Fp[8 * i + k]; Fj[k] = Fp[8 * j + k]; }
    float Hs[4][8];
#pragma unroll
    for (int m = 0; m < 4; ++m)
#pragma unroll
        for (int k = 0; k < 8; ++k) Hs[m][k] = Hp[8 * m + k];
    float Rs[4][4];
#pragma unroll
    for (int m = 0; m < 4; ++m)
#pragma unroll
        for (int o = 0; o < 4; ++o) Rs[m][o] = Rp[4 * m + o];
    const float Qij = Qp[lane];
    {
        float s0 = stdp[i];
        Pm[lane] = (i == j) ? s0 * s0 : 0.f;
    }
    __syncthreads();

    for (int t = 0; t < T_STEPS; ++t) {
        // ---- S1: Ppred = F P F^T + Q (fused quadratic form) ----
        float p[64];
#pragma unroll
        for (int q = 0; q < 16; ++q) {
            float4 v = Pm4[q];
            p[4 * q] = v.x; p[4 * q + 1] = v.y; p[4 * q + 2] = v.z; p[4 * q + 3] = v.w;
        }
        float u[8];
#pragma unroll
        for (int l = 0; l < 8; ++l) {
            float acc = 0.f;
#pragma unroll
            for (int k = 0; k < 8; ++k) acc += Fi[k] * p[8 * k + l];
            u[l] = acc;
        }
        float ppv = Qij;
#pragma unroll
        for (int l = 0; l < 8; ++l) ppv += u[l] * Fj[l];
        Pp[lane] = ppv;
        __syncthreads();

        // ---- S2: full PP into regs; T2 col j; S (4x4) via shuffles ----
        float pp[64];
#pragma unroll
        for (int q = 0; q < 16; ++q) {
            float4 v = Pp4[q];
            pp[4 * q] = v.x; pp[4 * q + 1] = v.y; pp[4 * q + 2] = v.z; pp[4 * q + 3] = v.w;
        }
        float ppc[8];
#pragma unroll
        for (int k = 0; k < 8; ++k) ppc[k] = Pp[8 * k + j];
        float t2c[4];  // T2[p][j] = sum_k H[p][k] PP[k][j]
#pragma unroll
        for (int pq = 0; pq < 4; ++pq) {
            float acc = 0.f;
#pragma unroll
            for (int k = 0; k < 8; ++k) acc += Hs[pq][k] * ppc[k];
            t2c[pq] = acc;
        }
        // S[a][b] = sum_l T2[a][l] H[b][l] + R  (a<=b, mirror)
        float S_[4][4];
#pragma unroll
        for (int a = 0; a < 4; ++a)
#pragma unroll
            for (int b = a; b < 4; ++b) S_[a][b] = Rs[a][b];
#pragma unroll
        for (int l = 0; l < 8; ++l) {
            float bc0 = __shfl(t2c[0], l), bc1 = __shfl(t2c[1], l);
            float bc2 = __shfl(t2c[2], l), bc3 = __shfl(t2c[3], l);
            S_[0][0] += bc0 * Hs[0][l]; S_[0][1] += bc0 * Hs[1][l];
            S_[0][2] += bc0 * Hs[2][l]; S_[0][3] += bc0 * Hs[3][l];
            S_[1][1] += bc1 * Hs[1][l]; S_[1][2] += bc1 * Hs[2][l];
            S_[1][3] += bc1 * Hs[3][l];
            S_[2][2] += bc2 * Hs[2][l]; S_[2][3] += bc2 * Hs[3][l];
            S_[3][3] += bc3 * Hs[3][l];
        }
        S_[1][0] = S_[0][1]; S_[2][0] = S_[0][2]; S_[3][0] = S_[0][3];
        S_[2][1] = S_[1][2]; S_[3][1] = S_[1][3]; S_[3][2] = S_[2][3];

        // ---- S3: SI = inv(S) redundantly per lane (adjugate) ----
        float SI[16];
        {
            float A0 = S_[0][0], A1 = S_[0][1], A2 = S_[0][2], A3 = S_[0][3];
            float A4 = S_[1][0], A5 = S_[1][1], A6 = S_[1][2], A7 = S_[1][3];
            float A8 = S_[2][0], A9 = S_[2][1], A10 = S_[2][2], A11 = S_[2][3];
            float A12 = S_[3][0], A13 = S_[3][1], A14 = S_[3][2], A15 = S_[3][3];
            float b00 = A0 * A5 - A1 * A4, b01 = A0 * A6 - A2 * A4;
            float b02 = A0 * A7 - A3 * A4, b03 = A1 * A6 - A2 * A5;
            float b04 = A1 * A7 - A3 * A5, b05 = A2 * A7 - A3 * A6;
            float b06 = A8 * A13 - A9 * A12, b07 = A8 * A14 - A10 * A12;
            float b08 = A8 * A15 - A11 * A12, b09 = A9 * A14 - A10 * A13;
            float b10 = A9 * A15 - A11 * A13, b11 = A10 * A15 - A11 * A14;
            float det = b00 * b11 - b01 * b10 + b02 * b09 + b03 * b08 -
                        b04 * b07 + b05 * b06;
            float rd = 1.0f / det;
            SI[0]  = ( A5 * b11 - A6 * b10 + A7 * b09) * rd;
            SI[1]  = (-A1 * b11 + A2 * b10 - A3 * b09) * rd;
            SI[2]  = ( A13 * b05 - A14 * b04 + A15 * b03) * rd;
            SI[3]  = (-A9 * b05 + A10 * b04 - A11 * b03) * rd;
            SI[4]  = (-A4 * b11 + A6 * b08 - A7 * b07) * rd;
            SI[5]  = ( A0 * b11 - A2 * b08 + A3 * b07) * rd;
            SI[6]  = (-A12 * b05 + A14 * b02 - A15 * b01) * rd;
            SI[7]  = ( A8 * b05 - A10 * b02 + A11 * b01) * rd;
            SI[8]  = ( A4 * b10 - A5 * b08 + A7 * b06) * rd;
            SI[9]  = (-A0 * b10 + A1 * b08 - A3 * b06) * rd;
            SI[10] = ( A12 * b04 - A13 * b02 + A15 * b00) * rd;
            SI[11] = (-A8 * b04 + A9 * b02 - A11 * b00) * rd;
            SI[12] = (-A4 * b09 + A5 * b07 - A6 * b06) * rd;
            SI[13] = ( A0 * b09 - A1 * b07 + A2 * b06) * rd;
            SI[14] = (-A12 * b03 + A13 * b01 - A14 * b00) * rd;
            SI[15] = ( A8 * b03 - A9 * b01 + A10 * b00) * rd;
        }
        // W col j: W[m][j] = sum_p SI[m][p] T2[p][j]  (= K[j][m])
        float w[4];
#pragma unroll
        for (int m = 0; m < 4; ++m) {
            float acc = 0.f;
#pragma unroll
            for (int pq = 0; pq < 4; ++pq) acc += SI[4 * m + pq] * t2c[pq];
            w[m] = acc;
        }
        if (i == 0)  // Kws[t][n=j][m] ; 8 lanes x 16B = 128B coalesced
            *(float4*)(Kws + t * 32 + j * 4) = make_float4(w[0], w[1], w[2], w[3]);
        // W col i via shuffle (source lane i holds col j'=i)
        float wi[4];
#pragma unroll
        for (int m = 0; m < 4; ++m) wi[m] = __shfl(w[m], i);

        // ---- S4: Joseph P_new[i][j] = (A PP A^T)[i][j] + (K R K^T)[i][j] ----
        float Ai[8], Aj[8];
#pragma unroll
        for (int k = 0; k < 8; ++k) {
            float a = (i == k) ? 1.f : 0.f;
            float b = (j == k) ? 1.f : 0.f;
#pragma unroll
            for (int m = 0; m < 4; ++m) {
                a -= wi[m] * Hs[m][k];
                b -= w[m] * Hs[m][k];
            }
            Ai[k] = a; Aj[k] = b;
        }
        float pn = 0.f;
#pragma unroll
        for (int l = 0; l < 8; ++l) {
            float tmp = 0.f;
#pragma unroll
            for (int k = 0; k < 8; ++k) tmp += Ai[k] * pp[8 * k + l];
            pn += tmp * Aj[l];
        }
#pragma unroll
        for (int o = 0; o < 4; ++o) {
            float e = 0.f;
#pragma unroll
            for (int m = 0; m < 4; ++m) e += wi[m] * Rs[m][o];
            pn += e * w[o];
        }
        Pm[lane] = pn;
        __syncthreads();
    }
}

// ---------------- Kernel 2: chunk propagators Phi_c = prod A_t -------------
// 8 blocks (one per chunk) x 64 lanes; lane (i,j) keeps full Phi column j.
__global__ __launch_bounds__(64) void kf_phi(
    const float* __restrict__ Fp, const float* __restrict__ Hp,
    const float* __restrict__ Kws, float* __restrict__ PHI)
{
    const int c = blockIdx.x;
    const int lane = threadIdx.x;
    const int i = lane >> 3, j = lane & 7;

    float Fv[8][8];
#pragma unroll
    for (int n = 0; n < 8; ++n)
#pragma unroll
        for (int k = 0; k < 8; ++k) Fv[n][k] = Fp[8 * n + k];
    float G[4][8];  // G = H F
#pragma unroll
    for (int m = 0; m < 4; ++m)
#pragma unroll
        for (int n = 0; n < 8; ++n) {
            float acc = 0.f;
#pragma unroll
            for (int k = 0; k < 8; ++k) acc += Hp[8 * m + k] * Fv[k][n];
            G[m][n] = acc;
        }

    float phi[8];
#pragma unroll
    for (int l = 0; l < 8; ++l) phi[l] = (l == j) ? 1.f : 0.f;

    for (int s = 0; s < LCHUNK; ++s) {
        const int t = c * LCHUNK + s;
        const float4* kq = (const float4*)(Kws + t * 32);
        float4 kv[8];
#pragma unroll
        for (int n = 0; n < 8; ++n) kv[n] = kq[n];
        float gp[4];
#pragma unroll
        for (int m = 0; m < 4; ++m) {
            float acc = 0.f;
#pragma unroll
            for (int l = 0; l < 8; ++l) acc += G[m][l] * phi[l];
            gp[m] = acc;
        }
        float ph2[8];
#pragma unroll
        for (int n = 0; n < 8; ++n) {
            float acc = 0.f;
#pragma unroll
            for (int l = 0; l < 8; ++l) acc += Fv[n][l] * phi[l];
            acc -= kv[n].x * gp[0] + kv[n].y * gp[1] + kv[n].z * gp[2] +
                   kv[n].w * gp[3];
            ph2[n] = acc;
        }
#pragma unroll
        for (int l = 0; l < 8; ++l) phi[l] = ph2[l];
    }
    if (i == 0) {  // lane (0,j) writes column j: PHI[c][l][j]
#pragma unroll
        for (int l = 0; l < 8; ++l) PHI[c * 64 + l * 8 + j] = phi[l];
    }
}

// ---------------- Kernel 3: particular solution per (batch, chunk) --------
__global__ __launch_bounds__(256) void kf_scan1(
    const float* __restrict__ xp, const float* __restrict__ Fp,
    const float* __restrict__ Hp, const float* __restrict__ Kws,
    float* __restrict__ V)
{
    const int g = blockIdx.x * 256 + threadIdx.x;
    const int b = g & (B_BATCH - 1);
    const int c = g >> 13;

    float Fv[N_ST][N_ST];
#pragma unroll
    for (int n = 0; n < N_ST; ++n)
#pragma unroll
        for (int k = 0; k < N_ST; ++k) Fv[n][k] = Fp[8 * n + k];
    float G[M_MEAS][N_ST];
#pragma unroll
    for (int m = 0; m < M_MEAS; ++m)
#pragma unroll
        for (int n = 0; n < N_ST; ++n) {
            float acc = 0.f;
#pragma unroll
            for (int k = 0; k < N_ST; ++k) acc += Hp[8 * m + k] * Fv[k][n];
            G[m][n] = acc;
        }

    float v[N_ST];
#pragma unroll
    for (int n = 0; n < N_ST; ++n) v[n] = 0.f;

    const float* xb = xp + (size_t)b * (M_MEAS * T_STEPS);
    for (int t4 = 0; t4 < LCHUNK / 4; ++t4) {
        const int tt4 = c * (LCHUNK / 4) + t4;
        float4 xq[M_MEAS];
#pragma unroll
        for (int m = 0; m < M_MEAS; ++m)
            xq[m] = *(const float4*)(xb + m * T_STEPS + tt4 * 4);
#pragma unroll
        for (int s = 0; s < 4; ++s) {
            const int t = c * LCHUNK + t4 * 4 + s;
            const float4* kq = (const float4*)(Kws + t * 32);
            float4 kv[N_ST];
#pragma unroll
            for (int n = 0; n < N_ST; ++n) kv[n] = kq[n];
            float resid[M_MEAS];
#pragma unroll
            for (int m = 0; m < M_MEAS; ++m) {
                float acc = 0.f;
#pragma unroll
                for (int n = 0; n < N_ST; ++n) acc += G[m][n] * v[n];
                const float xv = (s == 0) ? xq[m].x
                               : (s == 1) ? xq[m].y
                               : (s == 2) ? xq[m].z : xq[m].w;
                resid[m] = xv - acc;
            }
            float nv[N_ST];
#pragma unroll
            for (int n = 0; n < N_ST; ++n) {
                float acc = 0.f;
#pragma unroll
                for (int k = 0; k < N_ST; ++k) acc += Fv[n][k] * v[k];
                acc += kv[n].x * resid[0] + kv[n].y * resid[1] +
                       kv[n].z * resid[2] + kv[n].w * resid[3];
                nv[n] = acc;
            }
#pragma unroll
            for (int n = 0; n < N_ST; ++n) v[n] = nv[n];
        }
    }
    float4* vp = (float4*)(V + ((size_t)c * B_BATCH + b) * 8);
    vp[0] = make_float4(v[0], v[1], v[2], v[3]);
    vp[1] = make_float4(v[4], v[5], v[6], v[7]);
}

// ---------------- Kernel 4: reconstruct boundary state + outputs ----------
__global__ __launch_bounds__(256) void kf_scan2(
    const float* __restrict__ xp, const float* __restrict__ Fp,
    const float* __restrict__ Hp, const float* __restrict__ Kws,
    const float* __restrict__ PHI, const float* __restrict__ V,
    float* __restrict__ outp)
{
    const int g = blockIdx.x * 256 + threadIdx.x;
    const int b = g & (B_BATCH - 1);
    const int c = g >> 13;

    float Fv[N_ST][N_ST];
#pragma unroll
    for (int n = 0; n < N_ST; ++n)
#pragma unroll
        for (int k = 0; k < N_ST; ++k) Fv[n][k] = Fp[8 * n + k];
    float G[M_MEAS][N_ST];
#pragma unroll
    for (int m = 0; m < M_MEAS; ++m)
#pragma unroll
        for (int n = 0; n < N_ST; ++n) {
            float acc = 0.f;
#pragma unroll
            for (int k = 0; k < N_ST; ++k) acc += Hp[8 * m + k] * Fv[k][n];
            G[m][n] = acc;
        }

    // mu at chunk start: fold chunks 0..c-1 (uniform across wave: same c)
    float mu[N_ST];
#pragma unroll
    for (int n = 0; n < N_ST; ++n) mu[n] = 0.f;
    for (int c2 = 0; c2 < c; ++c2) {
        const float4* ph = (const float4*)(PHI + c2 * 64);
        const float4* vp = (const float4*)(V + ((size_t)c2 * B_BATCH + b) * 8);
        float4 va = vp[0], vb = vp[1];
        float m2[N_ST];
#pragma unroll
        for (int n = 0; n < N_ST; ++n) {
            float4 r0 = ph[n * 2], r1 = ph[n * 2 + 1];
            float acc = r0.x * mu[0] + r0.y * mu[1] + r0.z * mu[2] +
                        r0.w * mu[3] + r1.x * mu[4] + r1.y * mu[5] +
                        r1.z * mu[6] + r1.w * mu[7];
            acc += (n == 0) ? va.x : (n == 1) ? va.y : (n == 2) ? va.z
                 : (n == 3) ? va.w : (n == 4) ? vb.x : (n == 5) ? vb.y
                 : (n == 6) ? vb.z : vb.w;
            m2[n] = acc;
        }
#pragma unroll
        for (int n = 0; n < N_ST; ++n) mu[n] = m2[n];
    }

    const float* xb = xp + (size_t)b * (M_MEAS * T_STEPS);
    float* ob = outp + (size_t)b * (M_MEAS * T_STEPS);
    for (int t4 = 0; t4 < LCHUNK / 4; ++t4) {
        const int tt4 = c * (LCHUNK / 4) + t4;
        float4 xq[M_MEAS];
#pragma unroll
        for (int m = 0; m < M_MEAS; ++m)
            xq[m] = *(const float4*)(xb + m * T_STEPS + tt4 * 4);
        float obuf[M_MEAS][4];
#pragma unroll
        for (int s = 0; s < 4; ++s) {
            const int t = c * LCHUNK + t4 * 4 + s;
            const float4* kq = (const float4*)(Kws + t * 32);
            float4 kv[N_ST];
#pragma unroll
            for (int n = 0; n < N_ST; ++n) kv[n] = kq[n];
            float resid[M_MEAS];
#pragma unroll
            for (int m = 0; m < M_MEAS; ++m) {
                float acc = 0.f;
#pragma unroll
                for (int n = 0; n < N_ST; ++n) acc += G[m][n] * mu[n];
                obuf[m][s] = acc;
                const float xv = (s == 0) ? xq[m].x
                               : (s == 1) ? xq[m].y
                               : (s == 2) ? xq[m].z : xq[m].w;
                resid[m] = xv - acc;
            }
            float nmu[N_ST];
#pragma unroll
            for (int n = 0; n < N_ST; ++n) {
                float acc = 0.f;
#pragma unroll
                for (int k = 0; k < N_ST; ++k) acc += Fv[n][k] * mu[k];
                acc += kv[n].x * resid[0] + kv[n].y * resid[1] +
                       kv[n].z * resid[2] + kv[n].w * resid[3];
                nmu[n] = acc;
            }
#pragma unroll
            for (int n = 0; n < N_ST; ++n) mu[n] = nmu[n];
        }
#pragma unroll
        for (int m = 0; m < M_MEAS; ++m)
            *(float4*)(ob + m * T_STEPS + tt4 * 4) =
                make_float4(obuf[m][0], obuf[m][1], obuf[m][2], obuf[m][3]);
    }
}

// ---------------- Fallback (R4-proven): 1 thread per batch, serial T ------
__global__ __launch_bounds__(64) void kf_main_fb(
    const float* __restrict__ xp, const float* __restrict__ Fp,
    const float* __restrict__ Hp, const float* __restrict__ Kws,
    float* __restrict__ outp)
{
    const int b = blockIdx.x * 64 + threadIdx.x;
    float Fv[N_ST][N_ST];
#pragma unroll
    for (int n = 0; n < N_ST; ++n)
#pragma unroll
        for (int k = 0; k < N_ST; ++k) Fv[n][k] = Fp[8 * n + k];
    float G[M_MEAS][N_ST];
#pragma unroll
    for (int m = 0; m < M_MEAS; ++m)
#pragma unroll
        for (int n = 0; n < N_ST; ++n) {
            float acc = 0.f;
#pragma unroll
            for (int k = 0; k < N_ST; ++k) acc += Hp[8 * m + k] * Fv[k][n];
            G[m][n] = acc;
        }
    float mu[N_ST];
#pragma unroll
    for (int n = 0; n < N_ST; ++n) mu[n] = 0.f;
    const float* xb = xp + (size_t)b * (M_MEAS * T_STEPS);
    float* ob = outp + (size_t)b * (M_MEAS * T_STEPS);
    for (int t4 = 0; t4 < T_STEPS / 4; ++t4) {
        float4 xq[M_MEAS];
#pragma unroll
        for (int m = 0; m < M_MEAS; ++m)
            xq[m] = *(const float4*)(xb + m * T_STEPS + t4 * 4);
        float obuf[M_MEAS][4];
#pragma unroll
        for (int s = 0; s < 4; ++s) {
            const int t = t4 * 4 + s;
            const float4* kq = (const float4*)(Kws + t * 32);
            float4 kv[N_ST];
#pragma unroll
            for (int n = 0; n < N_ST; ++n) kv[n] = kq[n];
            float resid[M_MEAS];
#pragma unroll
            for (int m = 0; m < M_MEAS; ++m) {
                float acc = 0.f;
#pragma unroll
                for (int n = 0; n < N_ST; ++n) acc += G[m][n] * mu[n];
                obuf[m][s] = acc;
                const float xv = (s == 0) ? xq[m].x
                               : (s == 1) ? xq[m].y
                               : (s == 2) ? xq[m].z : xq[m].w;
                resid[m] = xv - acc;
            }
            float nmu[N_ST];
#pragma unroll
            for (int n = 0; n < N_ST; ++n) {
                float acc = 0.f;
#pragma unroll
                for (int k = 0; k < N_ST; ++k) acc += Fv[n][k] * mu[k];
                acc += kv[n].x * resid[0] + kv[n].y * resid[1] +
                       kv[n].z * resid[2] + kv[n].w * resid[3];
                nmu[n] = acc;
            }
#pragma unroll
            for (int n = 0; n < N_ST; ++n) mu[n] = nmu[n];
        }
#pragma unroll
        for (int m = 0; m < M_MEAS; ++m)
            *(float4*)(ob + m * T_STEPS + t4 * 4) =
                make_float4(obuf[m][0], obuf[m][1], obuf[m][2], obuf[m][3]);
    }
}

extern "C" void kernel_launch(void* const* d_in, const int* in_sizes, int n_in,
                              void* d_out, int out_size, void* d_ws, size_t ws_size,
                              hipStream_t stream) {
    const float* x    = (const float*)d_in[0];
    const float* F    = (const float*)d_in[1];
    const float* H    = (const float*)d_in[2];
    const float* Q    = (const float*)d_in[3];
    const float* R    = (const float*)d_in[4];
    const float* std0 = (const float*)d_in[5];
    float* out = (float*)d_out;
    float* wsf = (float*)d_ws;
    float* Kws = wsf + WS_K;

    kf_cov2<<<dim3(1), dim3(64), 0, stream>>>(F, H, Q, R, std0, Kws);

    if (ws_size >= (size_t)WS_NEED_BYTES) {
        float* PHI = wsf + WS_PHI;
        float* V   = wsf + WS_V;
        kf_phi<<<dim3(NCHUNK), dim3(64), 0, stream>>>(F, H, Kws, PHI);
        kf_scan1<<<dim3(B_BATCH * NCHUNK / 256), dim3(256), 0, stream>>>(
            x, F, H, Kws, V);
        kf_scan2<<<dim3(B_BATCH * NCHUNK / 256), dim3(256), 0, stream>>>(
            x, F, H, Kws, PHI, V, out);
    } else {
        kf_main_fb<<<dim3(B_BATCH / 64), dim3(64), 0, stream>>>(x, F, H, Kws, out);
    }
}